// Round 1
// baseline (504.853 us; speedup 1.0000x reference)
//
#include <hip/hip_runtime.h>

// Problem constants (from reference setup_inputs)
#define B_SAMPLES 50000
#define F_FEATS   100
#define T_TREES   2000
#define N_INTERNAL 63
#define N_LEAVES  64
#define DEPTH     6
#define N_CLASSES 10
#define LR        0.1f

#define BLK 128                     // samples (threads) per block
#define TREES_PER_GROUP 20          // concurrent traversals per thread (ILP)
#define N_GROUPS (T_TREES / TREES_PER_GROUP)   // 100
#define NODE_STRIDE 64              // padded per-tree node stride (8B nodes)

// ---- pre-pass: pack (feature, threshold) into int2 nodes[t*64 + i] ----
__global__ __launch_bounds__(256) void pack_nodes_kernel(
    const float* __restrict__ thresholds,
    const int*   __restrict__ features,
    int2*        __restrict__ nodes)
{
    int e = blockIdx.x * 256 + threadIdx.x;
    if (e < T_TREES * N_INTERNAL) {
        int t = e / N_INTERNAL;
        int i = e - t * N_INTERNAL;
        nodes[t * NODE_STRIDE + i] = make_int2(features[e], __float_as_int(thresholds[e]));
    }
}

// ---- main kernel: one thread = one sample; 20 trees traversed concurrently ----
__global__ __launch_bounds__(BLK) void forest_kernel(
    const float* __restrict__ x,
    const int2*  __restrict__ nodes,
    const float* __restrict__ leaves,
    float*       __restrict__ out)
{
    __shared__ float xs[F_FEATS * BLK];   // xs[f*BLK + tid] : bank = tid%32, conflict-free
    const int tid = threadIdx.x;
    const int b   = blockIdx.x * BLK + tid;
    const bool valid = (b < B_SAMPLES);

    // stage this sample's feature row into LDS (transposed)
    {
        const float4* xrow = reinterpret_cast<const float4*>(x + (size_t)b * F_FEATS);
        #pragma unroll
        for (int k = 0; k < F_FEATS / 4; ++k) {
            float4 v = valid ? xrow[k] : make_float4(0.f, 0.f, 0.f, 0.f);
            xs[(4 * k + 0) * BLK + tid] = v.x;
            xs[(4 * k + 1) * BLK + tid] = v.y;
            xs[(4 * k + 2) * BLK + tid] = v.z;
            xs[(4 * k + 3) * BLK + tid] = v.w;
        }
    }
    __syncthreads();

    float acc[N_CLASSES];
    #pragma unroll
    for (int c = 0; c < N_CLASSES; ++c) acc[c] = 0.f;

    for (int g = 0; g < N_GROUPS; ++g) {
        const int2*  nbase = nodes  + (size_t)g * TREES_PER_GROUP * NODE_STRIDE;
        const float* lbase = leaves + (size_t)g * TREES_PER_GROUP * N_LEAVES;

        int idx[TREES_PER_GROUP];
        #pragma unroll
        for (int j = 0; j < TREES_PER_GROUP; ++j) idx[j] = 0;

        #pragma unroll
        for (int lvl = 0; lvl < DEPTH; ++lvl) {
            int2 nd[TREES_PER_GROUP];
            // issue all 20 node loads (independent; L1/L2-resident)
            #pragma unroll
            for (int j = 0; j < TREES_PER_GROUP; ++j)
                nd[j] = nbase[j * NODE_STRIDE + idx[j]];
            // gather x from LDS, compare, descend
            #pragma unroll
            for (int j = 0; j < TREES_PER_GROUP; ++j) {
                float xv  = xs[nd[j].x * BLK + tid];
                float thr = __int_as_float(nd[j].y);
                idx[j] = 2 * idx[j] + 1 + (xv > thr ? 1 : 0);
            }
        }
        // leaf gather + class accumulate (j%N_CLASSES is compile-time after unroll)
        #pragma unroll
        for (int j = 0; j < TREES_PER_GROUP; ++j) {
            float lv = lbase[j * N_LEAVES + (idx[j] - (N_LEAVES - 1))];
            acc[j % N_CLASSES] += lv;
        }
    }

    if (valid) {
        float d[N_CLASSES];
        #pragma unroll
        for (int c = 0; c < N_CLASSES; ++c) d[c] = LR * acc[c];
        float m = d[0];
        #pragma unroll
        for (int c = 1; c < N_CLASSES; ++c) m = fmaxf(m, d[c]);
        float ssum = 0.f;
        #pragma unroll
        for (int c = 0; c < N_CLASSES; ++c) ssum += expf(d[c] - m);
        float lse = logf(ssum);
        float2* o = reinterpret_cast<float2*>(out + (size_t)b * N_CLASSES);
        #pragma unroll
        for (int c = 0; c < N_CLASSES / 2; ++c)
            o[c] = make_float2(d[2 * c] - m - lse, d[2 * c + 1] - m - lse);
    }
}

extern "C" void kernel_launch(void* const* d_in, const int* in_sizes, int n_in,
                              void* d_out, int out_size, void* d_ws, size_t ws_size,
                              hipStream_t stream) {
    const float* x          = (const float*)d_in[0];   // [50000,100] f32
    const float* thresholds = (const float*)d_in[1];   // [2000,63]  f32
    const float* leaves     = (const float*)d_in[2];   // [2000,64]  f32
    const int*   features   = (const int*)d_in[3];     // [2000,63]  i32
    // d_in[4] = classes (int64 arange, unused)

    int2* nodes = (int2*)d_ws;                         // 2000*64*8 = 1.0 MB scratch

    {
        int total = T_TREES * N_INTERNAL;
        int grid  = (total + 255) / 256;
        pack_nodes_kernel<<<grid, 256, 0, stream>>>(thresholds, features, nodes);
    }
    {
        int grid = (B_SAMPLES + BLK - 1) / BLK;        // 391 blocks
        forest_kernel<<<grid, BLK, 0, stream>>>(x, nodes, leaves, (float*)d_out);
    }
}

// Round 2
// 386.724 us; speedup vs baseline: 1.3055x; 1.3055x over previous
//
#include <hip/hip_runtime.h>

// Problem constants (from reference setup_inputs)
#define B_SAMPLES 50000
#define F_FEATS   100
#define T_TREES   2000
#define N_INTERNAL 63
#define N_LEAVES  64
#define DEPTH     6
#define N_CLASSES 10
#define LR        0.1f

#define BLK 128                       // samples (threads) per block
#define TREES_PER_GROUP 20            // concurrent traversals per thread (ILP)
#define NCHUNK 10                     // tree chunks (grid multiplier)
#define TREES_PER_CHUNK (T_TREES / NCHUNK)              // 200
#define GROUPS_PER_CHUNK (TREES_PER_CHUNK / TREES_PER_GROUP)  // 10
#define NODE_STRIDE 64                // padded per-tree node stride (8B nodes)
#define NSB ((B_SAMPLES + BLK - 1) / BLK)               // 391 sample-blocks

// ---- pre-pass: pack (feature, threshold) into int2 nodes[t*64 + i] ----
__global__ __launch_bounds__(256) void pack_nodes_kernel(
    const float* __restrict__ thresholds,
    const int*   __restrict__ features,
    int2*        __restrict__ nodes)
{
    int e = blockIdx.x * 256 + threadIdx.x;
    if (e < T_TREES * N_INTERNAL) {
        int t = e / N_INTERNAL;
        int i = e - t * N_INTERNAL;
        nodes[t * NODE_STRIDE + i] = make_int2(features[e], __float_as_int(thresholds[e]));
    }
}

// ---- main kernel: thread = sample, block = (sample-block, tree-chunk) ----
template<bool PARTIALS>
__global__ __launch_bounds__(BLK) void forest_kernel(
    const float* __restrict__ x,
    const int2*  __restrict__ nodes,
    const float* __restrict__ leaves,
    float*       __restrict__ accum)   // PARTIALS: [NCHUNK][B][10]; else [B][10] (atomic)
{
    __shared__ float xs[F_FEATS * BLK];   // xs[f*BLK + tid] : bank = tid%32, conflict-free
    const int tid   = threadIdx.x;
    const int chunk = blockIdx.x % NCHUNK;          // adjacent blocks share x slab (L2-hot)
    const int sb    = blockIdx.x / NCHUNK;
    const int b     = sb * BLK + tid;
    const bool valid = (b < B_SAMPLES);

    // stage this sample's feature row into LDS (transposed)
    {
        const float4* xrow = reinterpret_cast<const float4*>(x + (size_t)b * F_FEATS);
        #pragma unroll
        for (int k = 0; k < F_FEATS / 4; ++k) {
            float4 v = valid ? xrow[k] : make_float4(0.f, 0.f, 0.f, 0.f);
            xs[(4 * k + 0) * BLK + tid] = v.x;
            xs[(4 * k + 1) * BLK + tid] = v.y;
            xs[(4 * k + 2) * BLK + tid] = v.z;
            xs[(4 * k + 3) * BLK + tid] = v.w;
        }
    }
    __syncthreads();

    float acc[N_CLASSES];
    #pragma unroll
    for (int c = 0; c < N_CLASSES; ++c) acc[c] = 0.f;

    const int2*  cnodes  = nodes  + (size_t)chunk * TREES_PER_CHUNK * NODE_STRIDE;
    const float* cleaves = leaves + (size_t)chunk * TREES_PER_CHUNK * N_LEAVES;

    for (int g = 0; g < GROUPS_PER_CHUNK; ++g) {
        const int2*  nbase = cnodes  + (size_t)g * TREES_PER_GROUP * NODE_STRIDE;
        const float* lbase = cleaves + (size_t)g * TREES_PER_GROUP * N_LEAVES;

        int idx[TREES_PER_GROUP];
        #pragma unroll
        for (int j = 0; j < TREES_PER_GROUP; ++j) idx[j] = 0;

        #pragma unroll
        for (int lvl = 0; lvl < DEPTH; ++lvl) {
            int2 nd[TREES_PER_GROUP];
            #pragma unroll
            for (int j = 0; j < TREES_PER_GROUP; ++j)
                nd[j] = nbase[j * NODE_STRIDE + idx[j]];
            #pragma unroll
            for (int j = 0; j < TREES_PER_GROUP; ++j) {
                float xv  = xs[nd[j].x * BLK + tid];
                float thr = __int_as_float(nd[j].y);
                idx[j] = 2 * idx[j] + 1 + (xv > thr ? 1 : 0);
            }
        }
        // class of tree (chunk*200 + g*20 + j) is j%10 (200, 20 ≡ 0 mod 10)
        #pragma unroll
        for (int j = 0; j < TREES_PER_GROUP; ++j) {
            float lv = lbase[j * N_LEAVES + (idx[j] - (N_LEAVES - 1))];
            acc[j % N_CLASSES] += lv;
        }
    }

    if (valid) {
        if (PARTIALS) {
            float2* p = reinterpret_cast<float2*>(
                accum + ((size_t)chunk * B_SAMPLES + b) * N_CLASSES);
            #pragma unroll
            for (int c = 0; c < N_CLASSES / 2; ++c)
                p[c] = make_float2(acc[2 * c], acc[2 * c + 1]);
        } else {
            #pragma unroll
            for (int c = 0; c < N_CLASSES; ++c)
                atomicAdd(&accum[(size_t)b * N_CLASSES + c], acc[c]);
        }
    }
}

// ---- epilogue: sum partials, LR scale, log_softmax ----
template<bool PARTIALS>
__global__ __launch_bounds__(256) void softmax_kernel(
    const float* __restrict__ accum,
    float*       __restrict__ out)
{
    int b = blockIdx.x * 256 + threadIdx.x;
    if (b >= B_SAMPLES) return;

    float d[N_CLASSES];
    #pragma unroll
    for (int c = 0; c < N_CLASSES; ++c) d[c] = 0.f;

    if (PARTIALS) {
        for (int ch = 0; ch < NCHUNK; ++ch) {
            const float2* p = reinterpret_cast<const float2*>(
                accum + ((size_t)ch * B_SAMPLES + b) * N_CLASSES);
            #pragma unroll
            for (int c = 0; c < N_CLASSES / 2; ++c) {
                float2 v = p[c];
                d[2 * c]     += v.x;
                d[2 * c + 1] += v.y;
            }
        }
    } else {
        #pragma unroll
        for (int c = 0; c < N_CLASSES; ++c)
            d[c] = accum[(size_t)b * N_CLASSES + c];
    }

    #pragma unroll
    for (int c = 0; c < N_CLASSES; ++c) d[c] *= LR;
    float m = d[0];
    #pragma unroll
    for (int c = 1; c < N_CLASSES; ++c) m = fmaxf(m, d[c]);
    float ssum = 0.f;
    #pragma unroll
    for (int c = 0; c < N_CLASSES; ++c) ssum += expf(d[c] - m);
    float lse = logf(ssum);

    float2* o = reinterpret_cast<float2*>(out + (size_t)b * N_CLASSES);
    #pragma unroll
    for (int c = 0; c < N_CLASSES / 2; ++c)
        o[c] = make_float2(d[2 * c] - m - lse, d[2 * c + 1] - m - lse);
}

extern "C" void kernel_launch(void* const* d_in, const int* in_sizes, int n_in,
                              void* d_out, int out_size, void* d_ws, size_t ws_size,
                              hipStream_t stream) {
    const float* x          = (const float*)d_in[0];   // [50000,100] f32
    const float* thresholds = (const float*)d_in[1];   // [2000,63]  f32
    const float* leaves     = (const float*)d_in[2];   // [2000,64]  f32
    const int*   features   = (const int*)d_in[3];     // [2000,63]  i32
    // d_in[4] = classes (int64 arange, unused)

    const size_t nodes_bytes    = (size_t)T_TREES * NODE_STRIDE * sizeof(int2);       // 1.0 MB
    const size_t partials_bytes = (size_t)NCHUNK * B_SAMPLES * N_CLASSES * sizeof(float); // 20 MB
    const size_t accum_bytes    = (size_t)B_SAMPLES * N_CLASSES * sizeof(float);      // 2 MB

    int2*  nodes  = (int2*)d_ws;
    float* accbuf = (float*)((char*)d_ws + nodes_bytes);
    const bool use_partials = (ws_size >= nodes_bytes + partials_bytes);

    {
        int total = T_TREES * N_INTERNAL;
        pack_nodes_kernel<<<(total + 255) / 256, 256, 0, stream>>>(thresholds, features, nodes);
    }

    if (use_partials) {
        forest_kernel<true><<<NSB * NCHUNK, BLK, 0, stream>>>(x, nodes, leaves, accbuf);
        softmax_kernel<true><<<(B_SAMPLES + 255) / 256, 256, 0, stream>>>(accbuf, (float*)d_out);
    } else {
        hipMemsetAsync(accbuf, 0, accum_bytes, stream);
        forest_kernel<false><<<NSB * NCHUNK, BLK, 0, stream>>>(x, nodes, leaves, accbuf);
        softmax_kernel<false><<<(B_SAMPLES + 255) / 256, 256, 0, stream>>>(accbuf, (float*)d_out);
    }
}